// Round 7
// baseline (221.508 us; speedup 1.0000x reference)
//
#include <hip/hip_runtime.h>

typedef __bf16 bf16x8 __attribute__((ext_vector_type(8)));
typedef float  f32x4  __attribute__((ext_vector_type(4)));
typedef unsigned short u16;

#define NFRM 8
#define HW   1024
#define CDIM 640
#define NH   8
#define DH   80

__device__ __forceinline__ u16 bfb(float f) {
    return __builtin_bit_cast(u16, (__bf16)f);
}

// ---------------------------------------------------------------------------
// QKV projection: Y = hs(8192x640 f32) @ W(640x640 f32), output bf16, UNPADDED.
// z=0 -> Q [frame][head][1024][80] ; z=1 -> K same ; z=2 -> V^T [frame][head][80][1024]
// ---------------------------------------------------------------------------
__global__ __launch_bounds__(256) void qkv_gemm(
    const float* __restrict__ hs, const float* __restrict__ Wq,
    const float* __restrict__ Wk, const float* __restrict__ Wv,
    u16* __restrict__ Qb, u16* __restrict__ Kb, u16* __restrict__ Vt)
{
    __shared__ u16 Al[128 * 40];   // A tile 128x32 bf16, stride 40
    __shared__ u16 Bl[64 * 40];    // B^T tile 64x32 bf16, stride 40

    const int m0 = blockIdx.x * 128;
    const int n0 = blockIdx.y * 64;
    const int z  = blockIdx.z;
    const float* __restrict__ W = (z == 0) ? Wq : (z == 1 ? Wk : Wv);

    const int t    = threadIdx.x;
    const int lane = t & 63, w = t >> 6;
    const int wm = w >> 1, wn = w & 1;
    const int g = lane >> 4, l16 = lane & 15;

    f32x4 acc[4][2] = {};

    const int ar = t >> 3;        // 0..31
    const int ac = (t & 7) * 4;   // 0,4,...,28

    for (int k0 = 0; k0 < CDIM; k0 += 32) {
        #pragma unroll
        for (int i = 0; i < 4; ++i) {
            int r = ar + i * 32;
            float4 v = *reinterpret_cast<const float4*>(hs + (size_t)(m0 + r) * CDIM + k0 + ac);
            ushort4 u;
            u.x = bfb(v.x); u.y = bfb(v.y); u.z = bfb(v.z); u.w = bfb(v.w);
            *reinterpret_cast<ushort4*>(&Al[r * 40 + ac]) = u;
        }
        #pragma unroll
        for (int i = 0; i < 2; ++i) {
            int nn = ac + i * 32;
            float4 v = *reinterpret_cast<const float4*>(W + (size_t)(k0 + ar) * CDIM + n0 + nn);
            Bl[(nn + 0) * 40 + ar] = bfb(v.x);
            Bl[(nn + 1) * 40 + ar] = bfb(v.y);
            Bl[(nn + 2) * 40 + ar] = bfb(v.z);
            Bl[(nn + 3) * 40 + ar] = bfb(v.w);
        }
        __syncthreads();

        bf16x8 af[4], bfr[2];
        #pragma unroll
        for (int mf = 0; mf < 4; ++mf)
            af[mf] = *reinterpret_cast<const bf16x8*>(&Al[(wm * 64 + mf * 16 + l16) * 40 + g * 8]);
        #pragma unroll
        for (int nf = 0; nf < 2; ++nf)
            bfr[nf] = *reinterpret_cast<const bf16x8*>(&Bl[(wn * 32 + nf * 16 + l16) * 40 + g * 8]);
        #pragma unroll
        for (int mf = 0; mf < 4; ++mf)
            #pragma unroll
            for (int nf = 0; nf < 2; ++nf)
                acc[mf][nf] = __builtin_amdgcn_mfma_f32_16x16x32_bf16(af[mf], bfr[nf], acc[mf][nf], 0, 0, 0);
        __syncthreads();
    }

    // C frag layout: col=lane&15 (n), row=(lane>>4)*4+reg (m)
    #pragma unroll
    for (int mf = 0; mf < 4; ++mf) {
        const int mrow0 = m0 + wm * 64 + mf * 16 + g * 4;
        const int b = mrow0 >> 10, tok0 = mrow0 & 1023;
        #pragma unroll
        for (int nf = 0; nf < 2; ++nf) {
            const int n = n0 + wn * 32 + nf * 16 + l16;
            const int h = n / DH, d = n % DH;
            if (z < 2) {
                u16* dst = (z == 0 ? Qb : Kb);
                size_t base = ((size_t)((b * NH + h) * HW) + tok0) * DH + d;
                #pragma unroll
                for (int rr = 0; rr < 4; ++rr)
                    dst[base + (size_t)rr * DH] = bfb(acc[mf][nf][rr]);
            } else {
                ushort4 u;
                u.x = bfb(acc[mf][nf][0]); u.y = bfb(acc[mf][nf][1]);
                u.z = bfb(acc[mf][nf][2]); u.w = bfb(acc[mf][nf][3]);
                *reinterpret_cast<ushort4*>(&Vt[((size_t)((b * NH + h) * DH) + d) * HW + tok0]) = u;
            }
        }
    }
}

// ---------------------------------------------------------------------------
// Flash attention. Grid: (qtile 16, head 8, frame 8). 4 waves x 16 q-rows.
// dh=80 padded to 96 IN LDS only (zero-filled at staging).
// ---------------------------------------------------------------------------
__global__ __launch_bounds__(256) void attn_fwd(
    const u16* __restrict__ Qb, const u16* __restrict__ Kb,
    const u16* __restrict__ Vt, u16* __restrict__ Ob,
    const int* __restrict__ refidx)
{
    __shared__ u16 Kl[64 * 104];     // K (and Q-stage) tile [row][96 padded], stride 104
    __shared__ u16 Vl[80 * 72];      // V^T tile [d<80][key], stride 72
    __shared__ u16 Pl[4][16 * 72];   // per-wave P scratch [q][key], stride 72

    const int qt = blockIdx.x, h = blockIdx.y, b = blockIdx.z;
    const int t = threadIdx.x, lane = t & 63, w = t >> 6;
    const int g = lane >> 4, l16 = lane & 15;
    const int rfrm = refidx[0];
    const int qbase = qt * 64 + w * 16;

    const int srow = t >> 2;           // 0..63 staging row
    const int scol = (t & 3) * 24;     // 0,24,48,72

    // ---- stage this block's 64 Q rows (zero-padded to 96) and read A-fragments
    {
        const u16* src = Qb + ((size_t)((b * NH + h) * HW) + qt * 64 + srow) * DH + scol;
        u16* dst = &Kl[srow * 104 + scol];
        #pragma unroll
        for (int i = 0; i < 3; ++i) {
            const int col = scol + i * 8;
            if (col < DH)
                *reinterpret_cast<uint4*>(dst + i * 8) = *reinterpret_cast<const uint4*>(src + i * 8);
            else
                *reinterpret_cast<uint4*>(dst + i * 8) = uint4{0, 0, 0, 0};
        }
    }
    __syncthreads();
    bf16x8 qf[3];
    #pragma unroll
    for (int s = 0; s < 3; ++s)
        qf[s] = *reinterpret_cast<const bf16x8*>(&Kl[(w * 16 + l16) * 104 + s * 32 + g * 8]);
    __syncthreads();

    float m_i[4], l_i[4];
    #pragma unroll
    for (int rr = 0; rr < 4; ++rr) { m_i[rr] = -1e30f; l_i[rr] = 0.f; }
    f32x4 o[5] = {};
    const float scale = 0.11180339887498948f;  // 1/sqrt(80)

    for (int kt = 0; kt < 32; ++kt) {
        const int fb   = (kt < 16) ? b : rfrm;
        const int tok0 = (kt & 15) * 64;

        {   // stage K: 64 rows x 80 from global, cols 80..95 zeroed
            const u16* src = Kb + ((size_t)((fb * NH + h) * HW) + tok0 + srow) * DH + scol;
            u16* dst = &Kl[srow * 104 + scol];
            #pragma unroll
            for (int i = 0; i < 3; ++i) {
                const int col = scol + i * 8;
                if (col < DH)
                    *reinterpret_cast<uint4*>(dst + i * 8) = *reinterpret_cast<const uint4*>(src + i * 8);
                else
                    *reinterpret_cast<uint4*>(dst + i * 8) = uint4{0, 0, 0, 0};
            }
        }
        {   // stage V^T: 80 rows x 64 bf16; 640 16B chunks
            const u16* Vp = Vt + (size_t)((fb * NH + h) * DH) * HW + tok0;
            #pragma unroll
            for (int i = 0; i < 3; ++i) {
                int id = t + i * 256;
                if (id < 640) {
                    int d = id >> 3, c = (id & 7) * 8;
                    *reinterpret_cast<uint4*>(&Vl[d * 72 + c]) =
                        *reinterpret_cast<const uint4*>(Vp + (size_t)d * HW + c);
                }
            }
        }
        __syncthreads();

        // S = Q K^T : 4 key-groups x 3 k-steps
        f32x4 s4[4] = {};
        #pragma unroll
        for (int nf = 0; nf < 4; ++nf) {
            #pragma unroll
            for (int s = 0; s < 3; ++s) {
                bf16x8 kf = *reinterpret_cast<const bf16x8*>(&Kl[(nf * 16 + l16) * 104 + s * 32 + g * 8]);
                s4[nf] = __builtin_amdgcn_mfma_f32_16x16x32_bf16(qf[s], kf, s4[nf], 0, 0, 0);
            }
        }

        float ps[4][4];
        #pragma unroll
        for (int nf = 0; nf < 4; ++nf)
            #pragma unroll
            for (int rr = 0; rr < 4; ++rr)
                ps[nf][rr] = s4[nf][rr] * scale;

        // online softmax per q-row (rows live at reg rr, replicated over 16 lanes)
        #pragma unroll
        for (int rr = 0; rr < 4; ++rr) {
            float mx = fmaxf(fmaxf(ps[0][rr], ps[1][rr]), fmaxf(ps[2][rr], ps[3][rr]));
            mx = fmaxf(mx, __shfl_xor(mx, 1));
            mx = fmaxf(mx, __shfl_xor(mx, 2));
            mx = fmaxf(mx, __shfl_xor(mx, 4));
            mx = fmaxf(mx, __shfl_xor(mx, 8));
            const float mnew = fmaxf(m_i[rr], mx);
            const float corr = __expf(m_i[rr] - mnew);
            m_i[rr] = mnew;
            float rsum = 0.f;
            #pragma unroll
            for (int nf = 0; nf < 4; ++nf) {
                float p = __expf(ps[nf][rr] - mnew);
                ps[nf][rr] = p;
                rsum += p;
            }
            rsum += __shfl_xor(rsum, 1);
            rsum += __shfl_xor(rsum, 2);
            rsum += __shfl_xor(rsum, 4);
            rsum += __shfl_xor(rsum, 8);
            l_i[rr] = l_i[rr] * corr + rsum;
            #pragma unroll
            for (int of = 0; of < 5; ++of)
                o[of][rr] = o[of][rr] * corr;
        }

        // P (C-layout) -> LDS -> A-fragment layout (same-wave, in-order LDS)
        u16* Pw = &Pl[w][0];
        #pragma unroll
        for (int nf = 0; nf < 4; ++nf)
            #pragma unroll
            for (int rr = 0; rr < 4; ++rr)
                Pw[(g * 4 + rr) * 72 + nf * 16 + l16] = bfb(ps[nf][rr]);

        bf16x8 pa[2];
        #pragma unroll
        for (int ks = 0; ks < 2; ++ks)
            pa[ks] = *reinterpret_cast<const bf16x8*>(&Pw[l16 * 72 + ks * 32 + g * 8]);

        // O += P V : 5 d-groups (dh=80) x 2 key-steps
        #pragma unroll
        for (int of = 0; of < 5; ++of) {
            #pragma unroll
            for (int ks = 0; ks < 2; ++ks) {
                bf16x8 vf = *reinterpret_cast<const bf16x8*>(&Vl[(of * 16 + l16) * 72 + ks * 32 + g * 8]);
                o[of] = __builtin_amdgcn_mfma_f32_16x16x32_bf16(pa[ks], vf, o[of], 0, 0, 0);
            }
        }
        __syncthreads();
    }

    // epilogue: attn out [tok][640] bf16, col = h*80 + d
    #pragma unroll
    for (int of = 0; of < 5; ++of) {
        const int d = of * 16 + l16;
        #pragma unroll
        for (int rr = 0; rr < 4; ++rr) {
            const int tok = qbase + g * 4 + rr;
            const float val = o[of][rr] / l_i[rr];
            Ob[((size_t)(b * HW + tok)) * CDIM + h * DH + d] = bfb(val);
        }
    }
}

// ---------------------------------------------------------------------------
// Output projection: out = attnO(bf16 8192x640) @ Wo + bo, f32 out.
// ---------------------------------------------------------------------------
__global__ __launch_bounds__(256) void out_gemm(
    const u16* __restrict__ A, const float* __restrict__ W,
    const float* __restrict__ bias, float* __restrict__ out)
{
    __shared__ u16 Al[128 * 40];
    __shared__ u16 Bl[64 * 40];

    const int m0 = blockIdx.x * 128;
    const int n0 = blockIdx.y * 64;
    const int t = threadIdx.x;
    const int lane = t & 63, w = t >> 6;
    const int wm = w >> 1, wn = w & 1;
    const int g = lane >> 4, l16 = lane & 15;

    f32x4 acc[4][2] = {};
    const int br = t >> 3;
    const int bc = (t & 7) * 4;

    for (int k0 = 0; k0 < CDIM; k0 += 32) {
        #pragma unroll
        for (int i = 0; i < 2; ++i) {
            int id = t + i * 256;
            int rr = id >> 2, c = (id & 3) * 8;
            *reinterpret_cast<uint4*>(&Al[rr * 40 + c]) =
                *reinterpret_cast<const uint4*>(A + (size_t)(m0 + rr) * CDIM + k0 + c);
        }
        #pragma unroll
        for (int i = 0; i < 2; ++i) {
            int nn = bc + i * 32;
            float4 v = *reinterpret_cast<const float4*>(W + (size_t)(k0 + br) * CDIM + n0 + nn);
            Bl[(nn + 0) * 40 + br] = bfb(v.x);
            Bl[(nn + 1) * 40 + br] = bfb(v.y);
            Bl[(nn + 2) * 40 + br] = bfb(v.z);
            Bl[(nn + 3) * 40 + br] = bfb(v.w);
        }
        __syncthreads();

        bf16x8 af[4], bfr[2];
        #pragma unroll
        for (int mf = 0; mf < 4; ++mf)
            af[mf] = *reinterpret_cast<const bf16x8*>(&Al[(wm * 64 + mf * 16 + l16) * 40 + g * 8]);
        #pragma unroll
        for (int nf = 0; nf < 2; ++nf)
            bfr[nf] = *reinterpret_cast<const bf16x8*>(&Bl[(wn * 32 + nf * 16 + l16) * 40 + g * 8]);
        #pragma unroll
        for (int mf = 0; mf < 4; ++mf)
            #pragma unroll
            for (int nf = 0; nf < 2; ++nf)
                acc[mf][nf] = __builtin_amdgcn_mfma_f32_16x16x32_bf16(af[mf], bfr[nf], acc[mf][nf], 0, 0, 0);
        __syncthreads();
    }

    #pragma unroll
    for (int mf = 0; mf < 4; ++mf) {
        const int mrow0 = m0 + wm * 64 + mf * 16 + g * 4;
        #pragma unroll
        for (int nf = 0; nf < 2; ++nf) {
            const int n = n0 + wn * 32 + nf * 16 + l16;
            const float bs = bias[n];
            #pragma unroll
            for (int rr = 0; rr < 4; ++rr)
                out[(size_t)(mrow0 + rr) * CDIM + n] = acc[mf][nf][rr] + bs;
        }
    }
}

extern "C" void kernel_launch(void* const* d_in, const int* in_sizes, int n_in,
                              void* d_out, int out_size, void* d_ws, size_t ws_size,
                              hipStream_t stream) {
    const float* hs = (const float*)d_in[0];
    const float* Wq = (const float*)d_in[1];
    const float* Wk = (const float*)d_in[2];
    const float* Wv = (const float*)d_in[3];
    const float* Wo = (const float*)d_in[4];
    const float* bo = (const float*)d_in[5];
    const int*   ri = (const int*)d_in[6];
    float* out = (float*)d_out;

    const size_t QKV_ELEMS = (size_t)NFRM * NH * HW * DH;  // 5,242,880 bf16 each
    u16* Qb = (u16*)d_ws;
    u16* Kb = Qb + QKV_ELEMS;
    u16* Vt = Kb + QKV_ELEMS;
    u16* Ob = Vt + QKV_ELEMS;
    // total ws use: 4 * 10 MiB = 40 MiB; no memset needed (padding lives in LDS only)

    qkv_gemm<<<dim3(64, 10, 3), 256, 0, stream>>>(hs, Wq, Wk, Wv, Qb, Kb, Vt);
    attn_fwd<<<dim3(16, NH, NFRM), 256, 0, stream>>>(Qb, Kb, Vt, Ob, ri);
    out_gemm<<<dim3(64, 10), 256, 0, stream>>>(Ob, Wo, bo, out);
}